// Round 5
// baseline (233.525 us; speedup 1.0000x reference)
//
#include <hip/hip_runtime.h>
#include <hip/hip_fp16.h>
#include <math.h>

#define EPS 1e-20f
#define NPT 256
#define BB  512

// ---- complex float2 helpers ----
__device__ __forceinline__ float2 cadd(float2 a, float2 b){ return make_float2(a.x+b.x, a.y+b.y); }
__device__ __forceinline__ float2 csub(float2 a, float2 b){ return make_float2(a.x-b.x, a.y-b.y); }
__device__ __forceinline__ float2 cmul(float2 a, float2 b){ return make_float2(a.x*b.x - a.y*b.y, a.x*b.y + a.y*b.x); }
__device__ __forceinline__ float2 cmulc(float2 a, float c, float s){ return make_float2(a.x*c - a.y*s, a.x*s + a.y*c); }
__device__ __forceinline__ float2 cmulmi(float2 a){ return make_float2(a.y, -a.x); }   // * (-i)

__device__ __forceinline__ void bfly4(float2& c0, float2& c1, float2& c2, float2& c3) {
    float2 s0 = cadd(c0, c2), s1 = cadd(c1, c3);
    float2 d0 = csub(c0, c2), d1 = cmulmi(csub(c1, c3));
    c0 = cadd(s0, s1); c1 = cadd(d0, d1); c2 = csub(s0, s1); c3 = csub(d0, d1);
}

#define C16_1 0.9238795325112867f
#define S16_1 (-0.3826834323650898f)
#define C16_2 0.7071067811865476f
#define S16_2 (-0.7071067811865476f)
#define C16_3 0.3826834323650898f
#define S16_3 (-0.9238795325112867f)
#define C16_6 (-0.7071067811865476f)
#define S16_6 (-0.7071067811865476f)
#define C16_9 (-0.9238795325112867f)
#define S16_9 0.3826834323650898f

// in-place 16-pt DIF DFT; position p ends up holding frequency r4(p)=4(p&3)+(p>>2)
__device__ __forceinline__ void dft16(float2* x) {
    bfly4(x[0], x[4], x[8], x[12]);
    bfly4(x[1], x[5], x[9], x[13]);
    x[5]  = cmulc(x[5],  C16_1, S16_1);
    x[9]  = cmulc(x[9],  C16_2, S16_2);
    x[13] = cmulc(x[13], C16_3, S16_3);
    bfly4(x[2], x[6], x[10], x[14]);
    x[6]  = cmulc(x[6],  C16_2, S16_2);
    x[10] = cmulmi(x[10]);
    x[14] = cmulc(x[14], C16_6, S16_6);
    bfly4(x[3], x[7], x[11], x[15]);
    x[7]  = cmulc(x[7],  C16_3, S16_3);
    x[11] = cmulc(x[11], C16_6, S16_6);
    x[15] = cmulc(x[15], C16_9, S16_9);
    bfly4(x[0],  x[1],  x[2],  x[3]);
    bfly4(x[4],  x[5],  x[6],  x[7]);
    bfly4(x[8],  x[9],  x[10], x[11]);
    bfly4(x[12], x[13], x[14], x[15]);
}

#define R4C(p) ((((p) & 3) << 2) | ((p) >> 2))

// ---------------- fused kernel: one block per batch ----------------
// 1024 threads = 64 groups of 16 lanes; each group does 4 rows.
// Redesigned to fit the compiler's immovable 64-VGPR cap (rounds 1-4 spilled
// ~300MB of scratch traffic):
//  - no hreg[4][8]: I is scattered immediately into a 139KB LDS buffer in
//    final output order (row stride 272 halves = +8 banks/row).
//  - no LDS transpose buffer: 16x16 transpose done in-register via shfl_xor
//    butterfly (also removes the fp16 mid-FFT rounding).
//  - twiddle powers recomputed per row from w1 (saves 10 persistent VGPRs).
// Peak live set ~52 VGPRs. LDS = 2 + 139.3 KB -> 1 block/CU, 16 waves.
__global__ __launch_bounds__(1024) void k_fused(const float* __restrict__ xin,
                                                float* __restrict__ out) {
    __shared__ float2 El[256];
    __shared__ __align__(16) __half Ibuf[256 * 272];   // I * 2^-12, out-ordered
    __shared__ float wmax[16];

    const int tid = threadIdx.x;
    const int G   = tid >> 4;         // 0..63
    const int l   = tid & 15;
    const int b   = blockIdx.x;

    // stage raw E (normalization cancels in I/max(I))
    if (tid < 256)
        El[tid] = make_float2(xin[b * 512 + tid], xin[b * 512 + 256 + tid]);
    __syncthreads();

    const int k1 = R4C(l);
    float sn, cs;
    __sincosf(-0.024543692606170259f * (float)k1, &sn, &cs);   // -2pi/256 * k1
    const float2 w1 = make_float2(cs, sn);
    const int v = 127 - k1;
    float mx = 0.0f;

    #pragma unroll
    for (int r = 0; r < 4; ++r) {
        const int i = (r << 6) + G;   // row index 0..255

        float2 x[16];
        // ---- gate: x[n1] = E[16n1+l] * E[(16n1+l-i)&255] ----
        #pragma unroll
        for (int n1 = 0; n1 < 16; ++n1) {
            int j = 16 * n1 + l;
            x[n1] = cmul(El[j], El[(j - i) & 255]);
        }

        // ---- inner DFT over n1: x[p1] = Y[k1=r4(p1)][n2=l] ----
        dft16(x);

        // ---- 16x16 transpose across the 16-lane group, in-register ----
        // butterfly: after all rounds, new x[j]@lane l == old x[l]@lane j
        #pragma unroll
        for (int s = 1; s <= 8; s <<= 1) {
            const bool hi = (l & s) != 0;
            #pragma unroll
            for (int j0 = 0; j0 < 16; ++j0) {
                if (j0 & s) continue;          // compile-time pair skip
                const int j1 = j0 | s;
                float2 give = hi ? x[j0] : x[j1];
                float2 got;
                got.x = __shfl_xor(give.x, s, 64);   // xor<16 stays in group
                got.y = __shfl_xor(give.y, s, 64);
                x[j0] = hi ? got : x[j0];
                x[j1] = hi ? x[j1] : got;
            }
        }

        // ---- twiddle W256^{k1*n2}: powers recomputed from w1 (reg relief) ----
        {
            float2 w2 = cmul(w1, w1), w3 = cmul(w2, w1);
            float2 w4 = cmul(w2, w2), w8 = cmul(w4, w4), w12 = cmul(w8, w4);
            x[1]  = cmul(x[1],  w1);
            x[2]  = cmul(x[2],  w2);
            x[3]  = cmul(x[3],  w3);
            x[4]  = cmul(x[4],  w4);
            x[5]  = cmul(cmul(x[5],  w1), w4);
            x[6]  = cmul(cmul(x[6],  w2), w4);
            x[7]  = cmul(cmul(x[7],  w3), w4);
            x[8]  = cmul(x[8],  w8);
            x[9]  = cmul(cmul(x[9],  w1), w8);
            x[10] = cmul(cmul(x[10], w2), w8);
            x[11] = cmul(cmul(x[11], w3), w8);
            x[12] = cmul(x[12], w12);
            x[13] = cmul(cmul(x[13], w1), w12);
            x[14] = cmul(cmul(x[14], w2), w12);
            x[15] = cmul(cmul(x[15], w3), w12);
        }

        // ---- outer DFT over n2: x[p2] = X[k1 + 16*r4(p2)] ----
        dft16(x);

        // ---- I = |X|^2 -> LDS (out-ordered), track fp32 max ----
        // fftshift both axes + reverse last axis absorbed in (row, col):
        // row = i^128, col = (v - 16*r4(p2)) & 255 (consecutive per group)
        __half* irow = Ibuf + (i ^ 128) * 272;
        #pragma unroll
        for (int p2 = 0; p2 < 16; ++p2) {
            float I = x[p2].x * x[p2].x + x[p2].y * x[p2].y;
            mx = fmaxf(mx, I);
            irow[(v - 16 * R4C(p2)) & 255] = __float2half_rn(I * 0.000244140625f);
        }
    }

    // ---- block-level max: wave shfl reduce -> LDS -> all threads ----
    #pragma unroll
    for (int off = 32; off; off >>= 1) mx = fmaxf(mx, __shfl_xor(mx, off, 64));
    if ((tid & 63) == 0) wmax[tid >> 6] = mx;
    __syncthreads();   // fences Ibuf and wmax
    float bm = wmax[0];
    #pragma unroll
    for (int w = 1; w < 16; ++w) bm = fmaxf(bm, wmax[w]);
    const float inv = 4096.0f / fmaxf(bm, EPS);   // undo 2^-12 and normalize

    // ---- epilogue: stream Ibuf -> out, fully coalesced ----
    // float4 index f = j*1024 + tid  <->  row = f>>8... = 16j + wave, col = 4*lane
    const int l6 = tid & 63, w = tid >> 6;
    const size_t obase = ((size_t)b << 16);
    #pragma unroll
    for (int j = 0; j < 16; ++j) {
        const int row = 16 * j + w;
        float2 raw = *(const float2*)(Ibuf + row * 272 + 4 * l6);   // 2x half2, 8B
        float2 a = __half22float2(*(__half2*)&raw.x);
        float2 c = __half22float2(*(__half2*)&raw.y);
        float4 o = make_float4(a.x * inv, a.y * inv, c.x * inv, c.y * inv);
        *(float4*)&out[obase + 4096 * j + 4 * tid] = o;
    }
}

extern "C" void kernel_launch(void* const* d_in, const int* in_sizes, int n_in,
                              void* d_out, int out_size, void* d_ws, size_t ws_size,
                              hipStream_t stream) {
    const float* x = (const float*)d_in[0];
    float* out = (float*)d_out;
    k_fused<<<BB, 1024, 0, stream>>>(x, out);
}

// Round 6
// 199.560 us; speedup vs baseline: 1.1702x; 1.1702x over previous
//
#include <hip/hip_runtime.h>
#include <hip/hip_fp16.h>
#include <math.h>

#define EPS 1e-20f
#define NPT 256
#define BB  512

// ---- complex float2 helpers ----
__device__ __forceinline__ float2 cadd(float2 a, float2 b){ return make_float2(a.x+b.x, a.y+b.y); }
__device__ __forceinline__ float2 csub(float2 a, float2 b){ return make_float2(a.x-b.x, a.y-b.y); }
__device__ __forceinline__ float2 cmul(float2 a, float2 b){ return make_float2(a.x*b.x - a.y*b.y, a.x*b.y + a.y*b.x); }
__device__ __forceinline__ float2 cmulc(float2 a, float c, float s){ return make_float2(a.x*c - a.y*s, a.x*s + a.y*c); }
__device__ __forceinline__ float2 cmulmi(float2 a){ return make_float2(a.y, -a.x); }   // * (-i)

__device__ __forceinline__ void bfly4(float2& c0, float2& c1, float2& c2, float2& c3) {
    float2 s0 = cadd(c0, c2), s1 = cadd(c1, c3);
    float2 d0 = csub(c0, c2), d1 = cmulmi(csub(c1, c3));
    c0 = cadd(s0, s1); c1 = cadd(d0, d1); c2 = csub(s0, s1); c3 = csub(d0, d1);
}

#define C16_1 0.9238795325112867f
#define S16_1 (-0.3826834323650898f)
#define C16_2 0.7071067811865476f
#define S16_2 (-0.7071067811865476f)
#define C16_3 0.3826834323650898f
#define S16_3 (-0.9238795325112867f)
#define C16_6 (-0.7071067811865476f)
#define S16_6 (-0.7071067811865476f)
#define C16_9 (-0.9238795325112867f)
#define S16_9 0.3826834323650898f

// in-place 16-pt DIF DFT; position p ends up holding frequency r4(p)=4(p&3)+(p>>2)
__device__ __forceinline__ void dft16(float2* x) {
    bfly4(x[0], x[4], x[8], x[12]);
    bfly4(x[1], x[5], x[9], x[13]);
    x[5]  = cmulc(x[5],  C16_1, S16_1);
    x[9]  = cmulc(x[9],  C16_2, S16_2);
    x[13] = cmulc(x[13], C16_3, S16_3);
    bfly4(x[2], x[6], x[10], x[14]);
    x[6]  = cmulc(x[6],  C16_2, S16_2);
    x[10] = cmulmi(x[10]);
    x[14] = cmulc(x[14], C16_6, S16_6);
    bfly4(x[3], x[7], x[11], x[15]);
    x[7]  = cmulc(x[7],  C16_3, S16_3);
    x[11] = cmulc(x[11], C16_6, S16_6);
    x[15] = cmulc(x[15], C16_9, S16_9);
    bfly4(x[0],  x[1],  x[2],  x[3]);
    bfly4(x[4],  x[5],  x[6],  x[7]);
    bfly4(x[8],  x[9],  x[10], x[11]);
    bfly4(x[12], x[13], x[14], x[15]);
}

#define R4C(p) ((((p) & 3) << 2) | ((p) >> 2))

// ---------------- fused kernel: one block per batch ----------------
// 1024 threads = 64 groups of 16 lanes; each group does 4 rows.
// KEY CHANGE vs round 5: the r-loop is `#pragma unroll 1`. Rounds 1-5 fully
// unrolled it; the scheduler interleaved iterations (each ~50 live VGPRs)
// past the 64-reg cap -> scratch spill (~170MB fetch + ~290MB extra write).
// One iteration in isolation fits 64 regs. Epilogue capped at unroll 4 for
// the same reason (16 fully-unrolled float4 load/stores = up to 128 live).
__global__ __launch_bounds__(1024) void k_fused(const float* __restrict__ xin,
                                                float* __restrict__ out) {
    __shared__ float2 El[256];
    __shared__ __align__(16) __half Ibuf[256 * 272];   // I * 2^-12, out-ordered
    __shared__ float wmax[16];

    const int tid = threadIdx.x;
    const int G   = tid >> 4;         // 0..63
    const int l   = tid & 15;
    const int b   = blockIdx.x;

    // stage raw E (normalization cancels in I/max(I))
    if (tid < 256)
        El[tid] = make_float2(xin[b * 512 + tid], xin[b * 512 + 256 + tid]);
    __syncthreads();

    const int k1 = R4C(l);
    float sn, cs;
    __sincosf(-0.024543692606170259f * (float)k1, &sn, &cs);   // -2pi/256 * k1
    const float2 w1 = make_float2(cs, sn);
    const int v = 127 - k1;
    float mx = 0.0f;

    #pragma unroll 1
    for (int r = 0; r < 4; ++r) {
        const int i = (r << 6) + G;   // row index 0..255

        float2 x[16];
        // ---- gate: x[n1] = E[16n1+l] * E[(16n1+l-i)&255] ----
        #pragma unroll
        for (int n1 = 0; n1 < 16; ++n1) {
            int j = 16 * n1 + l;
            x[n1] = cmul(El[j], El[(j - i) & 255]);
        }

        // ---- inner DFT over n1: x[p1] = Y[k1=r4(p1)][n2=l] ----
        dft16(x);

        // ---- 16x16 transpose across the 16-lane group, in-register ----
        // butterfly: after all rounds, new x[j]@lane l == old x[l]@lane j
        #pragma unroll
        for (int s = 1; s <= 8; s <<= 1) {
            const bool hi = (l & s) != 0;
            #pragma unroll
            for (int j0 = 0; j0 < 16; ++j0) {
                if (j0 & s) continue;          // compile-time pair skip
                const int j1 = j0 | s;
                float2 give = hi ? x[j0] : x[j1];
                float2 got;
                got.x = __shfl_xor(give.x, s, 64);   // xor<16 stays in group
                got.y = __shfl_xor(give.y, s, 64);
                x[j0] = hi ? got : x[j0];
                x[j1] = hi ? x[j1] : got;
            }
        }

        // ---- twiddle W256^{k1*n2}: powers recomputed from w1 (reg relief) ----
        {
            float2 w2 = cmul(w1, w1), w3 = cmul(w2, w1);
            float2 w4 = cmul(w2, w2), w8 = cmul(w4, w4), w12 = cmul(w8, w4);
            x[1]  = cmul(x[1],  w1);
            x[2]  = cmul(x[2],  w2);
            x[3]  = cmul(x[3],  w3);
            x[4]  = cmul(x[4],  w4);
            x[5]  = cmul(cmul(x[5],  w1), w4);
            x[6]  = cmul(cmul(x[6],  w2), w4);
            x[7]  = cmul(cmul(x[7],  w3), w4);
            x[8]  = cmul(x[8],  w8);
            x[9]  = cmul(cmul(x[9],  w1), w8);
            x[10] = cmul(cmul(x[10], w2), w8);
            x[11] = cmul(cmul(x[11], w3), w8);
            x[12] = cmul(x[12], w12);
            x[13] = cmul(cmul(x[13], w1), w12);
            x[14] = cmul(cmul(x[14], w2), w12);
            x[15] = cmul(cmul(x[15], w3), w12);
        }

        // ---- outer DFT over n2: x[p2] = X[k1 + 16*r4(p2)] ----
        dft16(x);

        // ---- I = |X|^2 -> LDS (out-ordered), track fp32 max ----
        // fftshift both axes + reverse last axis absorbed in (row, col):
        // row = i^128, col = (v - 16*r4(p2)) & 255 (consecutive per group)
        __half* irow = Ibuf + (i ^ 128) * 272;
        #pragma unroll
        for (int p2 = 0; p2 < 16; ++p2) {
            float I = x[p2].x * x[p2].x + x[p2].y * x[p2].y;
            mx = fmaxf(mx, I);
            irow[(v - 16 * R4C(p2)) & 255] = __float2half_rn(I * 0.000244140625f);
        }
    }

    // ---- block-level max: wave shfl reduce -> LDS -> all threads ----
    #pragma unroll
    for (int off = 32; off; off >>= 1) mx = fmaxf(mx, __shfl_xor(mx, off, 64));
    if ((tid & 63) == 0) wmax[tid >> 6] = mx;
    __syncthreads();   // fences Ibuf and wmax
    float bm = wmax[0];
    #pragma unroll
    for (int w = 1; w < 16; ++w) bm = fmaxf(bm, wmax[w]);
    const float inv = 4096.0f / fmaxf(bm, EPS);   // undo 2^-12 and normalize

    // ---- epilogue: stream Ibuf -> out, fully coalesced ----
    // float4 index f = j*1024 + tid  <->  row = 16j + wave, col = 4*lane
    const int l6 = tid & 63, w = tid >> 6;
    const size_t obase = ((size_t)b << 16);
    #pragma unroll 4
    for (int j = 0; j < 16; ++j) {
        const int row = 16 * j + w;
        float2 raw = *(const float2*)(Ibuf + row * 272 + 4 * l6);   // 2x half2, 8B
        float2 a = __half22float2(*(__half2*)&raw.x);
        float2 c = __half22float2(*(__half2*)&raw.y);
        float4 o = make_float4(a.x * inv, a.y * inv, c.x * inv, c.y * inv);
        *(float4*)&out[obase + 4096 * j + 4 * tid] = o;
    }
}

extern "C" void kernel_launch(void* const* d_in, const int* in_sizes, int n_in,
                              void* d_out, int out_size, void* d_ws, size_t ws_size,
                              hipStream_t stream) {
    const float* x = (const float*)d_in[0];
    float* out = (float*)d_out;
    k_fused<<<BB, 1024, 0, stream>>>(x, out);
}